// Round 1
// baseline (437.500 us; speedup 1.0000x reference)
//
#include <hip/hip_runtime.h>
#include <hip/hip_bf16.h>

typedef unsigned short ushort_t;
typedef __attribute__((ext_vector_type(8))) short short8;
typedef __attribute__((ext_vector_type(4))) float f32x4;

#define B_SZ 8192
#define D_FT 784
#define K_PAD 800   // 25 * 32
#define THRESH 0.9f

__device__ inline unsigned short f2bf(float f) {
    unsigned int u = __float_as_uint(f);
    unsigned int r = (u + 0x7fffu + ((u >> 16) & 1u)) >> 16;
    return (unsigned short)r;
}

// One block per row: conv 2x2/s2 + bias -> unitary per 4-patch -> qf (LDS),
// row norm -> qn bf16 (padded to 800), logits + log_softmax -> log_probs.
__global__ __launch_bounds__(256) void preproc_kernel(
    const float* __restrict__ x, const float* __restrict__ conv_w,
    const float* __restrict__ conv_b, const float* __restrict__ unitary,
    const float* __restrict__ lin_w, const float* __restrict__ lin_b,
    float* __restrict__ log_probs, ushort_t* __restrict__ qn)
{
    __shared__ float xr[784];
    __shared__ float qf[784];
    __shared__ float red[64];

    const int b = blockIdx.x;
    const int t = threadIdx.x;
    const int lane = t & 63;
    const int wv = t >> 6;

    // stage x row (784 floats = 196 float4)
    if (t < 196) ((float4*)xr)[t] = ((const float4*)(x + (size_t)b * 784))[t];
    __syncthreads();

    float sumsq = 0.f;
    if (t < 196) {
        const int c = t / 49, p = t % 49;
        const float w00 = conv_w[c*4+0], w01 = conv_w[c*4+1];
        const float w10 = conv_w[c*4+2], w11 = conv_w[c*4+3];
        const float bc = conv_b[c];
        float feat[4];
        #pragma unroll
        for (int j = 0; j < 4; ++j) {
            const int s = 4*p + j;
            const int h = s / 14, wq = s % 14;
            const float* px = &xr[(2*h)*28 + 2*wq];
            feat[j] = bc + w00*px[0] + w01*px[1] + w10*px[28] + w11*px[29];
        }
        #pragma unroll
        for (int w = 0; w < 4; ++w) {
            float v = unitary[w*4+0]*feat[0] + unitary[w*4+1]*feat[1]
                    + unitary[w*4+2]*feat[2] + unitary[w*4+3]*feat[3];
            qf[4*t + w] = v;
            sumsq += v * v;
        }
    }
    // block reduce sumsq
    #pragma unroll
    for (int off = 32; off; off >>= 1) sumsq += __shfl_down(sumsq, off, 64);
    if (lane == 0) red[wv] = sumsq;
    __syncthreads();
    if (t == 0) red[8] = 1.0f / (sqrtf(red[0]+red[1]+red[2]+red[3]) + 1e-12f);
    __syncthreads();
    const float inv = red[8];

    // write qn bf16, zero-padded to K_PAD
    for (int k = t; k < K_PAD; k += 256) {
        float v = (k < D_FT) ? qf[k] * inv : 0.f;
        qn[(size_t)b * K_PAD + k] = f2bf(v);
    }

    // logits: 10 dot products of length 784
    float acc[10];
    #pragma unroll
    for (int cl = 0; cl < 10; ++cl) acc[cl] = 0.f;
    for (int k = t; k < D_FT; k += 256) {
        const float v = qf[k];
        #pragma unroll
        for (int cl = 0; cl < 10; ++cl) acc[cl] += v * lin_w[cl*784 + k];
    }
    #pragma unroll
    for (int cl = 0; cl < 10; ++cl)
        #pragma unroll
        for (int off = 32; off; off >>= 1) acc[cl] += __shfl_down(acc[cl], off, 64);
    __syncthreads();   // protect red[] reuse (everyone has read red[8])
    if (lane == 0) {
        #pragma unroll
        for (int cl = 0; cl < 10; ++cl) red[cl*4 + wv] = acc[cl];
    }
    __syncthreads();
    if (t == 0) {
        float lg[10], mx = -1e30f;
        #pragma unroll
        for (int cl = 0; cl < 10; ++cl) {
            lg[cl] = red[cl*4] + red[cl*4+1] + red[cl*4+2] + red[cl*4+3] + lin_b[cl];
            mx = fmaxf(mx, lg[cl]);
        }
        float se = 0.f;
        #pragma unroll
        for (int cl = 0; cl < 10; ++cl) se += expf(lg[cl] - mx);
        const float lse = mx + logf(se);
        #pragma unroll
        for (int cl = 0; cl < 10; ++cl) log_probs[(size_t)b*10 + cl] = lg[cl] - lse;
    }
}

// 128x128 tile Gram GEMM: C = qn @ qn^T, fid = C^2, adj = (fid>=0.9 && i!=j)
// 256 threads = 4 waves (2x2), each wave 64x64 via 4x4 tiles of 16x16x32 bf16 MFMA.
__global__ __launch_bounds__(256) void gram_kernel(
    const ushort_t* __restrict__ qn, float* __restrict__ adj)
{
    __shared__ ushort_t ldsA[128*32] __attribute__((aligned(16)));
    __shared__ ushort_t ldsB[128*32] __attribute__((aligned(16)));

    const int t = threadIdx.x;
    const int bc = blockIdx.x, br = blockIdx.y;
    const int lane = t & 63, wave = t >> 6;
    const int wr = wave >> 1, wc = wave & 1;
    const int quad = lane >> 4, l16 = lane & 15;

    const int rowA0 = br * 128, rowB0 = bc * 128;
    // staging chunks: 512 x 16B per tile, 2 per thread
    const int r0 = t >> 2,          kk0 = (t & 3) << 3;
    const int r1 = (t + 256) >> 2,  kk1 = ((t + 256) & 3) << 3;

    f32x4 acc[4][4] = {};

    for (int kt = 0; kt < 25; ++kt) {
        const int k0 = kt * 32;
        uint4 a0 = *(const uint4*)(qn + (size_t)(rowA0 + r0) * K_PAD + k0 + kk0);
        uint4 a1 = *(const uint4*)(qn + (size_t)(rowA0 + r1) * K_PAD + k0 + kk1);
        uint4 b0 = *(const uint4*)(qn + (size_t)(rowB0 + r0) * K_PAD + k0 + kk0);
        uint4 b1 = *(const uint4*)(qn + (size_t)(rowB0 + r1) * K_PAD + k0 + kk1);
        *(uint4*)&ldsA[r0*32 + kk0] = a0;
        *(uint4*)&ldsA[r1*32 + kk1] = a1;
        *(uint4*)&ldsB[r0*32 + kk0] = b0;
        *(uint4*)&ldsB[r1*32 + kk1] = b1;
        __syncthreads();

        short8 af[4], bf[4];
        #pragma unroll
        for (int mi = 0; mi < 4; ++mi)
            af[mi] = *(const short8*)&ldsA[(wr*64 + mi*16 + l16)*32 + quad*8];
        #pragma unroll
        for (int ni = 0; ni < 4; ++ni)
            bf[ni] = *(const short8*)&ldsB[(wc*64 + ni*16 + l16)*32 + quad*8];
        #pragma unroll
        for (int mi = 0; mi < 4; ++mi)
            #pragma unroll
            for (int ni = 0; ni < 4; ++ni)
                acc[mi][ni] = __builtin_amdgcn_mfma_f32_16x16x32_bf16(
                    af[mi], bf[ni], acc[mi][ni], 0, 0, 0);
        __syncthreads();
    }

    // epilogue: fid = c^2, threshold, zero diagonal
    #pragma unroll
    for (int mi = 0; mi < 4; ++mi) {
        const int gr0 = br*128 + wr*64 + mi*16 + quad*4;
        #pragma unroll
        for (int ni = 0; ni < 4; ++ni) {
            const int gc = bc*128 + wc*64 + ni*16 + l16;
            const f32x4 v = acc[mi][ni];
            #pragma unroll
            for (int r = 0; r < 4; ++r) {
                const int gr = gr0 + r;
                const float f = v[r] * v[r];
                adj[(size_t)gr * B_SZ + gc] = (f >= THRESH && gr != gc) ? 1.0f : 0.0f;
            }
        }
    }
}

extern "C" void kernel_launch(void* const* d_in, const int* in_sizes, int n_in,
                              void* d_out, int out_size, void* d_ws, size_t ws_size,
                              hipStream_t stream) {
    const float* x       = (const float*)d_in[0];
    const float* conv_w  = (const float*)d_in[1];
    const float* conv_b  = (const float*)d_in[2];
    const float* unitary = (const float*)d_in[3];
    const float* lin_w   = (const float*)d_in[4];
    const float* lin_b   = (const float*)d_in[5];

    float* log_probs = (float*)d_out;
    float* adj       = (float*)d_out + (size_t)B_SZ * 10;
    ushort_t* qn     = (ushort_t*)d_ws;   // [8192, 800] bf16

    preproc_kernel<<<B_SZ, 256, 0, stream>>>(x, conv_w, conv_b, unitary,
                                             lin_w, lin_b, log_probs, qn);
    gram_kernel<<<dim3(64, 64), 256, 0, stream>>>(qn, adj);
}